// Round 4
// baseline (506.681 us; speedup 1.0000x reference)
//
#include <hip/hip_runtime.h>

// GATraj fused kernels for MI355X (gfx950) — round 4.
//
// Math simplifications (verified passing rounds 1-3):
//  * LN over the size-1 W_a channel == be_a exactly -> Pos is uniform 1/cnt_i
//    over masked neighbors. W_a/b_a/g_a unused.
//  * tmp @ W_g splits; h_i/h_j parts are per-node precomputes.
//  * LN of (c0*w0 + c1*w1 + b_r) is analytic via 6 moments of centered W_r.
//
// Round-4 changes (r3 post-mortem: ~2500 VALU insts/wave, __frcp_rn & precise
// OCML transcendentals are the bloat; ~100us of 150 lives outside the pair
// kernel in prep/final/launch overhead):
//  * native rcp/rsq/exp2 everywhere (error << 0.105 threshold)
//  * final kernel FUSED into pair kernel: per-row atomic "last wave closes
//    the row" (agent-scope fences, split-K pattern); 3 launches -> 2
//  * per-tile BH gathers issued before the MFMAs (latency under matrix work)

#define NN 768
#define DD 64
#define CHP 32  // pairs per wave-chunk
#define NCH 24  // chunk slots per row
#define EPSF 1e-5f
#define LOG2E 1.44269504f

typedef __attribute__((ext_vector_type(8))) short short8;
typedef __attribute__((ext_vector_type(4))) float float4v;
typedef __attribute__((ext_vector_type(2))) float float2v;

__device__ __forceinline__ unsigned short f2bf(float f) {
  unsigned int u = __float_as_uint(f);
  u += 0x7fffu + ((u >> 16) & 1u);  // round-to-nearest-even
  return (unsigned short)(u >> 16);
}

__device__ __forceinline__ float fast_sigmoid(float x) {
  float e = __builtin_amdgcn_exp2f(-LOG2E * x);
  return __builtin_amdgcn_rcpf(1.f + e);
}

__device__ __forceinline__ float fast_tanh(float x) {
  float e = __builtin_amdgcn_exp2f(fminf(x, 20.f) * (2.f * LOG2E));
  return (e - 1.f) * __builtin_amdgcn_rcpf(e + 1.f);
}

// ---------------------------------------------------------------------------
// Prep kernel, grid = 768 + 1 + 192 blocks x 256 threads.
//   bid < 768  : compact masked-j list -> Lst/cnt_g, zero done_g, and emit the
//                degenerate output for cnt==0 rows
//   bid == 768 : W_r moments -> KT/evec, GB pack, transposed bf16 Wg_lo
//   bid > 768  : A_pre / {B_pre,hidden} packed GEMVs (wave per row)
// ---------------------------------------------------------------------------
__global__ __launch_bounds__(256) void prep_kernel(
    const float* __restrict__ hidden, const float* __restrict__ Wg,
    const float* __restrict__ bg, const float* __restrict__ Wr,
    const float* __restrict__ br, const float* __restrict__ gr,
    const float* __restrict__ ber, const float* __restrict__ gg,
    const float* __restrict__ beg, const int* __restrict__ nei,
    const float* __restrict__ cn, const float* __restrict__ bw,
    const float* __restrict__ gw, const float* __restrict__ bew,
    float* __restrict__ A_pre, float2v* __restrict__ BH,
    float4v* __restrict__ KT, float2v* __restrict__ GB,
    float* __restrict__ evec, unsigned short* __restrict__ WgT,
    unsigned short* __restrict__ Lst, int* __restrict__ cnt_g,
    int* __restrict__ done_g, float* __restrict__ out) {
  const int bid = blockIdx.x;
  const int tid = threadIdx.x;

  if (bid < NN) {
    __shared__ int cLds;
    if (tid == 0) cLds = 0;
    __syncthreads();
#pragma unroll
    for (int rep = 0; rep < 3; ++rep) {
      int jj = tid + rep * 256;
      if (nei[bid * NN + jj] > 0) {
        int idx = atomicAdd(&cLds, 1);
        Lst[bid * NN + idx] = (unsigned short)jj;
      }
    }
    __syncthreads();
    if (tid == 0) {
      cnt_g[bid] = cLds;
      done_g[bid] = 0;
    }
    if (cLds == 0 && tid < 64) {
      // Degenerate row: H_sum == 0 -> x = bw; LN(x); out.
      int d = tid;
      float dotv = bw[d];
      float s = dotv, qq = dotv * dotv;
#pragma unroll
      for (int m = 1; m < 64; m <<= 1) {
        s += __shfl_xor(s, m);
        qq += __shfl_xor(qq, m);
      }
      float u = s * (1.f / DD);
      float var = qq * (1.f / DD) - u * u;
      float inv = __builtin_amdgcn_rsqf(var + EPSF);
      float val = fmaxf(0.f, fmaf(gw[d], (dotv - u) * inv, bew[d]));
      float Cv = val + cn[bid * DD + d];
      out[bid * DD + d] = hidden[bid * DD + d] + fast_tanh(Cv);
      out[NN * DD + bid * DD + d] = Cv;
    }
    return;
  }

  if (bid == NN) {
    // Transposed bf16 pack of Wg rows 0..63: WgT[n*64+k] = bf16(Wg[k*64+n])
    for (int idx = tid; idx < DD * DD; idx += 256) {
      int n = idx >> 6, k = idx & 63;
      WgT[idx] = f2bf(Wg[k * DD + n]);
    }
    if (tid < 64) {  // wave 0: W_r moments, KT, GB, evec
      int t = tid;
      float w0 = Wr[t], w1 = Wr[DD + t], bb = br[t];
      float m0 = w0, m1 = w1, mb = bb;
      for (int m = 1; m < 64; m <<= 1) {
        m0 += __shfl_xor(m0, m);
        m1 += __shfl_xor(m1, m);
        mb += __shfl_xor(mb, m);
      }
      m0 *= (1.f / DD);
      m1 *= (1.f / DD);
      mb *= (1.f / DD);
      float a0 = w0 - m0, a1 = w1 - m1, ab = bb - mb;
      float grt = gr[t];
      float4v kt;
      kt[0] = grt * a0;
      kt[1] = grt * a1;
      kt[2] = grt * ab;
      kt[3] = ber[t];
      KT[t] = kt;
      float2v gb;
      gb[0] = gg[t];
      gb[1] = beg[t];
      GB[t] = gb;
      float e00 = a0 * a0, e11 = a1 * a1, ebb = ab * ab;
      float e01 = a0 * a1, e0b = a0 * ab, e1b = a1 * ab;
      for (int m = 1; m < 64; m <<= 1) {
        e00 += __shfl_xor(e00, m);
        e11 += __shfl_xor(e11, m);
        ebb += __shfl_xor(ebb, m);
        e01 += __shfl_xor(e01, m);
        e0b += __shfl_xor(e0b, m);
        e1b += __shfl_xor(e1b, m);
      }
      if (t == 0) {
        evec[0] = e00 * (1.f / DD);
        evec[1] = e11 * (1.f / DD);
        evec[2] = ebb * (1.f / DD);
        evec[3] = e01 * (1.f / DD);
        evec[4] = e0b * (1.f / DD);
        evec[5] = e1b * (1.f / DD);
      }
    }
    return;
  }

  // A_pre / BH: 4 rows per block, one wave per row.
  const int w = tid >> 6;
  const int lane = tid & 63;
  const int i = (bid - NN - 1) * 4 + w;
  float hv = hidden[i * DD + lane];
  float a = bg[lane];
  float b = 0.f;
#pragma unroll 8
  for (int k = 0; k < DD; ++k) {
    float hk = __shfl(hv, k);
    a = fmaf(hk, Wg[(DD + k) * DD + lane], a);
    b = fmaf(hk, Wg[(2 * DD + k) * DD + lane], b);
  }
  A_pre[i * DD + lane] = a;
  float2v bh2;
  bh2[0] = b;
  bh2[1] = hv;
  BH[i * DD + lane] = bh2;
}

// ---------------------------------------------------------------------------
// Pair kernel: 4 independent waves per 256-block; wave = (row i, 32-pair
// chunk c). grid = 768*6 blocks. No __syncthreads. Last wave of each row
// closes the row (sums partials, W_w GEMV, LN, outputs).
// ---------------------------------------------------------------------------
__global__ __launch_bounds__(256) void pair_kernel(
    const float2v* __restrict__ corr2, const float* __restrict__ A_pre,
    const float2v* __restrict__ BH, const float4v* __restrict__ KT,
    const float2v* __restrict__ GB, const float* __restrict__ evec,
    const unsigned short* __restrict__ WgT,
    const unsigned short* __restrict__ Lst, const int* __restrict__ cnt_g,
    float* __restrict__ Hpart, int* __restrict__ done_g,
    const float* __restrict__ hidden, const float* __restrict__ cn,
    const float* __restrict__ bea, const float* __restrict__ Ww,
    const float* __restrict__ bw, const float* __restrict__ gw,
    const float* __restrict__ bew, float* __restrict__ out) {
  __shared__ __align__(16) unsigned short Rt[4][CHP * 72];  // per-wave slice

  const int b = blockIdx.x;
  const int tid = threadIdx.x;
  const int wid = tid >> 6;
  const int i = b / 6;
  const int c = (b - i * 6) * 4 + wid;
  const int cnt = cnt_g[i];
  const int base = c * CHP;
  if (base >= cnt) return;  // whole-wave exit; no barriers anywhere

  const int lane = tid & 63;
  const int quad = lane >> 4;
  const int nl = lane & 15;
  const int p32 = lane & 31;
  const int h = lane >> 5;  // k-half for R build

  // Pair data: lane handles pair p32 (lanes 32-63 mirror 0-31).
  int pg = base + p32;
  int jp = (int)Lst[i * NN + (pg < cnt ? pg : base)];
  float2v cc = corr2[i * NN + jp];
  const float e00 = evec[0], e11 = evec[1], ebb = evec[2];
  const float e01 = evec[3], e0b = evec[4], e1b = evec[5];
  float var = cc[0] * cc[0] * e00 + cc[1] * cc[1] * e11 + ebb +
              2.f * (cc[0] * cc[1] * e01 + cc[0] * e0b + cc[1] * e1b);
  float iv = __builtin_amdgcn_rsqf(var + EPSF);

  // B fragments of Wg_lo (16B contiguous from transposed pack).
  short8 Bf[2][4];
#pragma unroll
  for (int ks = 0; ks < 2; ++ks)
#pragma unroll
    for (int nt = 0; nt < 4; ++nt)
      __builtin_memcpy(&Bf[ks][nt],
                       &WgT[(nt * 16 + nl) * DD + ks * 32 + quad * 8], 16);

  // Epilogue per-lane constants: d = nt*16 + nl.
  float gg4[4], beg4[4], pre4[4];
#pragma unroll
  for (int nt = 0; nt < 4; ++nt) {
    int d = nt * 16 + nl;
    float2v gb = GB[d];
    gg4[nt] = gb[0];
    beg4[nt] = gb[1];
    pre4[nt] = A_pre[i * DD + d];
  }

  // R build, pair-orientation: lane writes R[p32][k] for k in [32h, 32h+32).
  {
    short8 wbuf;
#pragma unroll
    for (int kk = 0; kk < 32; ++kk) {
      float4v kt = KT[h * 32 + kk];
      float s3 = fmaf(cc[0], kt[0], fmaf(cc[1], kt[1], kt[2]));
      float r = fmaxf(0.f, fmaf(iv, s3, kt[3]));
      wbuf[kk & 7] = (short)f2bf(r);
      if ((kk & 7) == 7)
        __builtin_memcpy(&Rt[wid][p32 * 72 + h * 32 + (kk & ~7)], &wbuf, 16);
    }
  }
  // Make all lanes' ds_writes visible to this wave's ds_reads.
  __builtin_amdgcn_fence(__ATOMIC_ACQ_REL, "workgroup");

  float accT[4] = {0.f, 0.f, 0.f, 0.f};

#pragma unroll
  for (int t = 0; t < 2; ++t) {
    // Gather targets first (independent of MFMA) so latency hides under it.
    int jpr[4];
    float pv[4];
#pragma unroll
    for (int rr = 0; rr < 4; ++rr) {
      int pl = t * 16 + quad * 4 + rr;  // C layout: m = quad*4 + reg
      jpr[rr] = __shfl(jp, pl);
      pv[rr] = (base + pl < cnt) ? 1.f : 0.f;
    }
    float2v bh2[4][4];
#pragma unroll
    for (int rr = 0; rr < 4; ++rr)
#pragma unroll
      for (int nt = 0; nt < 4; ++nt)
        bh2[rr][nt] = BH[jpr[rr] * DD + nt * 16 + nl];

    short8 a0, a1;
    __builtin_memcpy(&a0, &Rt[wid][(t * 16 + nl) * 72 + quad * 8], 16);
    __builtin_memcpy(&a1, &Rt[wid][(t * 16 + nl) * 72 + 32 + quad * 8], 16);
    float4v acc[4];
#pragma unroll
    for (int nt = 0; nt < 4; ++nt) {
      float4v z = {0.f, 0.f, 0.f, 0.f};
      z = __builtin_amdgcn_mfma_f32_16x16x32_bf16(a0, Bf[0][nt], z, 0, 0, 0);
      z = __builtin_amdgcn_mfma_f32_16x16x32_bf16(a1, Bf[1][nt], z, 0, 0, 0);
      acc[nt] = z;
    }

    float y[4][4];
#pragma unroll
    for (int nt = 0; nt < 4; ++nt)
#pragma unroll
      for (int rr = 0; rr < 4; ++rr)
        y[nt][rr] = acc[nt][rr] + pre4[nt] + bh2[rr][nt][0];
#pragma unroll
    for (int rr = 0; rr < 4; ++rr) {
      float s = y[0][rr] + y[1][rr] + y[2][rr] + y[3][rr];
      float qq = y[0][rr] * y[0][rr] + y[1][rr] * y[1][rr] +
                 y[2][rr] * y[2][rr] + y[3][rr] * y[3][rr];
#pragma unroll
      for (int m = 1; m < 16; m <<= 1) {
        s += __shfl_xor(s, m);
        qq += __shfl_xor(qq, m);
      }
      float u = s * (1.f / DD);
      float vv = qq * (1.f / DD) - u * u;
      float inv = __builtin_amdgcn_rsqf(vv + EPSF);
#pragma unroll
      for (int nt = 0; nt < 4; ++nt) {
        float g = fmaf(gg4[nt], (y[nt][rr] - u) * inv, beg4[nt]);
        float gate = fast_sigmoid(g);
        accT[nt] = fmaf(gate * pv[rr], bh2[rr][nt][1], accT[nt]);
      }
    }
  }

  // Reduce over quads; lanes 0..15 write the 64-channel partial.
#pragma unroll
  for (int nt = 0; nt < 4; ++nt) {
    accT[nt] += __shfl_xor(accT[nt], 16);
    accT[nt] += __shfl_xor(accT[nt], 32);
  }
  if (lane < 16) {
#pragma unroll
    for (int nt = 0; nt < 4; ++nt)
      Hpart[(i * NCH + c) * DD + nt * 16 + nl] = accT[nt];
  }

  // ----- fused final: last wave of row i closes the row -----
  __builtin_amdgcn_fence(__ATOMIC_RELEASE, "agent");
  int old = 0;
  if (lane == 0)
    old = __hip_atomic_fetch_add(&done_g[i], 1, __ATOMIC_ACQ_REL,
                                 __HIP_MEMORY_SCOPE_AGENT);
  old = __shfl(old, 0);
  const int nactive = (cnt + CHP - 1) >> 5;
  if (old != nactive - 1) return;
  __builtin_amdgcn_fence(__ATOMIC_ACQUIRE, "agent");

  const int d = lane;
  float hs = 0.f;
  for (int c2 = 0; c2 < nactive; ++c2) hs += Hpart[(i * NCH + c2) * DD + d];
  float tta = fmaxf(bea[0], 0.f);
  float wgt = (tta > 0.f) ? __builtin_amdgcn_rcpf((float)cnt)
                          : (1.f / (float)NN);
  hs *= wgt;  // H_sum[i][d]

  float dotv = bw[d];
#pragma unroll 8
  for (int k = 0; k < DD; ++k) {
    float hk = __shfl(hs, k);
    dotv = fmaf(hk, Ww[k * DD + d], dotv);
  }
  float s = dotv, qq = dotv * dotv;
#pragma unroll
  for (int m = 1; m < 64; m <<= 1) {
    s += __shfl_xor(s, m);
    qq += __shfl_xor(qq, m);
  }
  float u = s * (1.f / DD);
  float var2 = qq * (1.f / DD) - u * u;
  float inv = __builtin_amdgcn_rsqf(var2 + EPSF);
  float val = fmaxf(0.f, fmaf(gw[d], (dotv - u) * inv, bew[d]));
  float Cv = val + cn[i * DD + d];
  out[i * DD + d] = hidden[i * DD + d] + fast_tanh(Cv);
  out[NN * DD + i * DD + d] = Cv;
}

extern "C" void kernel_launch(void* const* d_in, const int* in_sizes, int n_in,
                              void* d_out, int out_size, void* d_ws,
                              size_t ws_size, hipStream_t stream) {
  const float* corr = (const float*)d_in[0];
  const int* nei = (const int*)d_in[1];
  // d_in[2] nei_num: unused by the reference math
  const float* hidden = (const float*)d_in[3];
  const float* cn = (const float*)d_in[4];
  const float* Wr = (const float*)d_in[5];
  const float* br = (const float*)d_in[6];
  const float* gr = (const float*)d_in[7];
  const float* ber = (const float*)d_in[8];
  const float* Wg = (const float*)d_in[9];
  const float* bg = (const float*)d_in[10];
  const float* gg = (const float*)d_in[11];
  const float* beg = (const float*)d_in[12];
  // d_in[13..15] W_a/b_a/g_a: cancel analytically
  const float* bea = (const float*)d_in[16];
  const float* Ww = (const float*)d_in[17];
  const float* bw = (const float*)d_in[18];
  const float* gw = (const float*)d_in[19];
  const float* bew = (const float*)d_in[20];
  float* out = (float*)d_out;

  float* ws = (float*)d_ws;
  // float-offset layout (all 16B aligned):
  float* A_pre = ws;                              // 49152
  float2v* BH = (float2v*)(ws + 49152);           // 98304 floats
  float4v* KT = (float4v*)(ws + 147456);          // 256 floats
  float2v* GB = (float2v*)(ws + 147712);          // 128 floats
  float* evec = ws + 147840;                      // 8 (pad to 16)
  unsigned short* WgT = (unsigned short*)(ws + 147856);  // 4096 shorts
  int* cnt_g = (int*)(ws + 149904);               // 768
  unsigned short* Lst = (unsigned short*)(ws + 150672);  // 768*768 shorts
  float* Hpart = ws + 445584;                     // 768*24*64 = 1179648
  int* done_g = (int*)(ws + 1625232);             // 768

  prep_kernel<<<NN + 1 + NN / 4, 256, 0, stream>>>(
      hidden, Wg, bg, Wr, br, gr, ber, gg, beg, nei, cn, bw, gw, bew, A_pre,
      BH, KT, GB, evec, WgT, Lst, cnt_g, done_g, out);
  pair_kernel<<<NN * 6, 256, 0, stream>>>(
      (const float2v*)corr, A_pre, BH, KT, GB, evec, WgT, Lst, cnt_g, Hpart,
      done_g, hidden, cn, bea, Ww, bw, gw, bew, out);
}

// Round 5
// 148.644 us; speedup vs baseline: 3.4087x; 3.4087x over previous
//
#include <hip/hip_runtime.h>

// GATraj fused kernels for MI355X (gfx950) — round 5.
//
// Math simplifications (verified passing rounds 1-4):
//  * LN over the size-1 W_a channel == be_a exactly -> Pos is uniform 1/cnt_i
//    over masked neighbors (or 1/768 if be_a<=0). W_a/b_a/g_a unused.
//  * tmp @ W_g splits; h_i/h_j parts are per-node precomputes (A_pre, BH).
//  * LN of (c0*w0 + c1*w1 + b_r) is analytic via 6 moments of centered W_r.
//
// Round-5 (r4 post-mortem: agent-scope fences per wave -> L2 writeback storm,
// 433us @ VALUBusy 3.7%): revert to the in-block row-closing monolith (r1's
// 46.9us structure, no fences), keeping the proven r3/r4 wins: shuffle-free
// R-build (KT), transposed WgT pack, packed {B_pre,hidden} gathers, native
// rcp/rsq/exp2, barrier-free per-wave chunks + next-chunk prefetch.
// 2 launches, no device-scope atomics.

#define NN 768
#define DD 64
#define CHP 32  // pairs per wave-chunk
#define EPSF 1e-5f
#define LOG2E 1.44269504f

typedef __attribute__((ext_vector_type(8))) short short8;
typedef __attribute__((ext_vector_type(4))) float float4v;
typedef __attribute__((ext_vector_type(2))) float float2v;

__device__ __forceinline__ unsigned short f2bf(float f) {
  unsigned int u = __float_as_uint(f);
  u += 0x7fffu + ((u >> 16) & 1u);  // round-to-nearest-even
  return (unsigned short)(u >> 16);
}

__device__ __forceinline__ float fast_sigmoid(float x) {
  float e = __builtin_amdgcn_exp2f(-LOG2E * x);
  return __builtin_amdgcn_rcpf(1.f + e);
}

__device__ __forceinline__ float fast_tanh(float x) {
  float e = __builtin_amdgcn_exp2f(fminf(x, 20.f) * (2.f * LOG2E));
  return (e - 1.f) * __builtin_amdgcn_rcpf(e + 1.f);
}

// ---------------------------------------------------------------------------
// Prep kernel, grid = 193 blocks x 256 threads:
//   bid < 192  : A_pre / {B_pre,hidden} packed GEMVs (wave per row, 4 rows)
//   bid == 192 : transposed bf16 Wg_lo pack + W_r moments -> KT/GB/evec
// ---------------------------------------------------------------------------
__global__ __launch_bounds__(256) void prep_kernel(
    const float* __restrict__ hidden, const float* __restrict__ Wg,
    const float* __restrict__ bg, const float* __restrict__ Wr,
    const float* __restrict__ br, const float* __restrict__ gr,
    const float* __restrict__ ber, const float* __restrict__ gg,
    const float* __restrict__ beg, float* __restrict__ A_pre,
    float2v* __restrict__ BH, float4v* __restrict__ KT,
    float2v* __restrict__ GB, float* __restrict__ evec,
    unsigned short* __restrict__ WgT) {
  const int bid = blockIdx.x;
  const int tid = threadIdx.x;

  if (bid == NN / 4) {
    // Transposed bf16 pack of Wg rows 0..63: WgT[n*64+k] = bf16(Wg[k*64+n])
    for (int idx = tid; idx < DD * DD; idx += 256) {
      int n = idx >> 6, k = idx & 63;
      WgT[idx] = f2bf(Wg[k * DD + n]);
    }
    if (tid < 64) {  // wave 0: W_r moments, KT, GB, evec
      int t = tid;
      float w0 = Wr[t], w1 = Wr[DD + t], bb = br[t];
      float m0 = w0, m1 = w1, mb = bb;
      for (int m = 1; m < 64; m <<= 1) {
        m0 += __shfl_xor(m0, m);
        m1 += __shfl_xor(m1, m);
        mb += __shfl_xor(mb, m);
      }
      m0 *= (1.f / DD);
      m1 *= (1.f / DD);
      mb *= (1.f / DD);
      float a0 = w0 - m0, a1 = w1 - m1, ab = bb - mb;
      float grt = gr[t];
      float4v kt;
      kt[0] = grt * a0;
      kt[1] = grt * a1;
      kt[2] = grt * ab;
      kt[3] = ber[t];
      KT[t] = kt;
      float2v gb;
      gb[0] = gg[t];
      gb[1] = beg[t];
      GB[t] = gb;
      float e00 = a0 * a0, e11 = a1 * a1, ebb = ab * ab;
      float e01 = a0 * a1, e0b = a0 * ab, e1b = a1 * ab;
      for (int m = 1; m < 64; m <<= 1) {
        e00 += __shfl_xor(e00, m);
        e11 += __shfl_xor(e11, m);
        ebb += __shfl_xor(ebb, m);
        e01 += __shfl_xor(e01, m);
        e0b += __shfl_xor(e0b, m);
        e1b += __shfl_xor(e1b, m);
      }
      if (t == 0) {
        evec[0] = e00 * (1.f / DD);
        evec[1] = e11 * (1.f / DD);
        evec[2] = ebb * (1.f / DD);
        evec[3] = e01 * (1.f / DD);
        evec[4] = e0b * (1.f / DD);
        evec[5] = e1b * (1.f / DD);
      }
    }
    return;
  }

  // A_pre / BH: 4 rows per block, one wave per row.
  const int w = tid >> 6;
  const int lane = tid & 63;
  const int i = bid * 4 + w;
  float hv = hidden[i * DD + lane];
  float a = bg[lane];
  float b = 0.f;
#pragma unroll 8
  for (int k = 0; k < DD; ++k) {
    float hk = __shfl(hv, k);
    a = fmaf(hk, Wg[(DD + k) * DD + lane], a);
    b = fmaf(hk, Wg[(2 * DD + k) * DD + lane], b);
  }
  A_pre[i * DD + lane] = a;
  float2v bh2;
  bh2[0] = b;
  bh2[1] = hv;
  BH[i * DD + lane] = bh2;
}

// ---------------------------------------------------------------------------
// Monolith: one block per row i (768 x 256). Compact in LDS; 4 waves process
// disjoint 32-pair chunks barrier-free (next-chunk prefetch); in-block final.
// ---------------------------------------------------------------------------
__global__ __launch_bounds__(256) void gat_kernel(
    const int* __restrict__ nei, const float2v* __restrict__ corr2,
    const float* __restrict__ A_pre, const float2v* __restrict__ BH,
    const float4v* __restrict__ KT, const float2v* __restrict__ GB,
    const float* __restrict__ evec, const unsigned short* __restrict__ WgT,
    const float* __restrict__ hidden, const float* __restrict__ cn,
    const float* __restrict__ bea, const float* __restrict__ Ww,
    const float* __restrict__ bw, const float* __restrict__ gw,
    const float* __restrict__ bew, float* __restrict__ out) {
  __shared__ __align__(16) unsigned short Rt[4][CHP * 72];  // per-wave slice
  __shared__ short Lst[NN];
  __shared__ float red[4][DD];
  __shared__ int cLds;

  const int i = blockIdx.x;
  const int tid = threadIdx.x;
  const int wid = tid >> 6;
  const int lane = tid & 63;
  const int quad = lane >> 4;
  const int nl = lane & 15;
  const int p32 = lane & 31;
  const int h = lane >> 5;  // k-half for R build

  if (tid == 0) cLds = 0;
  __syncthreads();
#pragma unroll
  for (int rep = 0; rep < 3; ++rep) {
    int jj = tid + rep * 256;
    if (nei[i * NN + jj] > 0) {
      int idx = atomicAdd(&cLds, 1);
      Lst[idx] = (short)jj;
    }
  }
  __syncthreads();
  const int cnt = cLds;

  // Constants hoisted out of the chunk loop.
  const float e00 = evec[0], e11 = evec[1], ebb = evec[2];
  const float e01 = evec[3], e0b = evec[4], e1b = evec[5];

  // B fragments of Wg_lo (16B contiguous from transposed pack).
  short8 Bf[2][4];
#pragma unroll
  for (int ks = 0; ks < 2; ++ks)
#pragma unroll
    for (int nt = 0; nt < 4; ++nt)
      __builtin_memcpy(&Bf[ks][nt],
                       &WgT[(nt * 16 + nl) * DD + ks * 32 + quad * 8], 16);

  // Epilogue per-lane constants: d = nt*16 + nl.
  float gg4[4], beg4[4], pre4[4];
#pragma unroll
  for (int nt = 0; nt < 4; ++nt) {
    int d = nt * 16 + nl;
    float2v gb = GB[d];
    gg4[nt] = gb[0];
    beg4[nt] = gb[1];
    pre4[nt] = A_pre[i * DD + d];
  }

  float accT[4] = {0.f, 0.f, 0.f, 0.f};

  // Wave wid processes chunks wid, wid+4, wid+8, ... with 1-chunk prefetch.
  int c = wid;
  bool act = (c * CHP < cnt);
  int jp = 0;
  float2v cc;
  cc[0] = 0.f;
  cc[1] = 0.f;
  if (act) {
    int pg = c * CHP + p32;
    jp = (int)Lst[pg < cnt ? pg : 0];
    cc = corr2[i * NN + jp];
  }

  while (act) {
    // Prefetch next chunk's pair list + corr (hides latency under this chunk).
    int c2 = c + 4;
    bool act2 = (c2 * CHP < cnt);
    int jpn = 0;
    float2v ccn;
    ccn[0] = 0.f;
    ccn[1] = 0.f;
    if (act2) {
      int pg = c2 * CHP + p32;
      jpn = (int)Lst[pg < cnt ? pg : 0];
      ccn = corr2[i * NN + jpn];
    }

    float var = cc[0] * cc[0] * e00 + cc[1] * cc[1] * e11 + ebb +
                2.f * (cc[0] * cc[1] * e01 + cc[0] * e0b + cc[1] * e1b);
    float iv = __builtin_amdgcn_rsqf(var + EPSF);

    // R build, pair-orientation: lane writes R[p32][k], k in [32h, 32h+32).
    {
      short8 wbuf;
#pragma unroll
      for (int kk = 0; kk < 32; ++kk) {
        float4v kt = KT[h * 32 + kk];
        float s3 = fmaf(cc[0], kt[0], fmaf(cc[1], kt[1], kt[2]));
        float r = fmaxf(0.f, fmaf(iv, s3, kt[3]));
        wbuf[kk & 7] = (short)f2bf(r);
        if ((kk & 7) == 7)
          __builtin_memcpy(&Rt[wid][p32 * 72 + h * 32 + (kk & ~7)], &wbuf, 16);
      }
    }
    // Make all lanes' ds_writes visible to this wave's ds_reads.
    __builtin_amdgcn_fence(__ATOMIC_ACQ_REL, "workgroup");

#pragma unroll
    for (int t = 0; t < 2; ++t) {
      // Gather targets first (independent of MFMA) so latency hides under it.
      int jpr[4];
      float pv[4];
#pragma unroll
      for (int rr = 0; rr < 4; ++rr) {
        int pl = t * 16 + quad * 4 + rr;  // C layout: m = quad*4 + reg
        jpr[rr] = __shfl(jp, pl);
        pv[rr] = (c * CHP + pl < cnt) ? 1.f : 0.f;
      }
      float2v bh2[4][4];
#pragma unroll
      for (int rr = 0; rr < 4; ++rr)
#pragma unroll
        for (int nt = 0; nt < 4; ++nt)
          bh2[rr][nt] = BH[jpr[rr] * DD + nt * 16 + nl];

      short8 a0, a1;
      __builtin_memcpy(&a0, &Rt[wid][(t * 16 + nl) * 72 + quad * 8], 16);
      __builtin_memcpy(&a1, &Rt[wid][(t * 16 + nl) * 72 + 32 + quad * 8], 16);
      float4v acc[4];
#pragma unroll
      for (int nt = 0; nt < 4; ++nt) {
        float4v z = {0.f, 0.f, 0.f, 0.f};
        z = __builtin_amdgcn_mfma_f32_16x16x32_bf16(a0, Bf[0][nt], z, 0, 0, 0);
        z = __builtin_amdgcn_mfma_f32_16x16x32_bf16(a1, Bf[1][nt], z, 0, 0, 0);
        acc[nt] = z;
      }

      float y[4][4];
#pragma unroll
      for (int nt = 0; nt < 4; ++nt)
#pragma unroll
        for (int rr = 0; rr < 4; ++rr)
          y[nt][rr] = acc[nt][rr] + pre4[nt] + bh2[rr][nt][0];
#pragma unroll
      for (int rr = 0; rr < 4; ++rr) {
        float s = y[0][rr] + y[1][rr] + y[2][rr] + y[3][rr];
        float qq = y[0][rr] * y[0][rr] + y[1][rr] * y[1][rr] +
                   y[2][rr] * y[2][rr] + y[3][rr] * y[3][rr];
#pragma unroll
        for (int m = 1; m < 16; m <<= 1) {
          s += __shfl_xor(s, m);
          qq += __shfl_xor(qq, m);
        }
        float u = s * (1.f / DD);
        float vv = qq * (1.f / DD) - u * u;
        float inv = __builtin_amdgcn_rsqf(vv + EPSF);
#pragma unroll
        for (int nt = 0; nt < 4; ++nt) {
          float g = fmaf(gg4[nt], (y[nt][rr] - u) * inv, beg4[nt]);
          float gate = fast_sigmoid(g);
          accT[nt] = fmaf(gate * pv[rr], bh2[rr][nt][1], accT[nt]);
        }
      }
    }

    c = c2;
    act = act2;
    jp = jpn;
    cc = ccn;
  }

  // Per-wave partials -> LDS (all 4 waves always reach here; no early return).
#pragma unroll
  for (int nt = 0; nt < 4; ++nt) {
    accT[nt] += __shfl_xor(accT[nt], 16);
    accT[nt] += __shfl_xor(accT[nt], 32);
  }
  if (lane < 16) {
#pragma unroll
    for (int nt = 0; nt < 4; ++nt) red[wid][nt * 16 + nl] = accT[nt];
  }
  __syncthreads();

  if (tid < 64) {  // wave 0 closes the row
    const int d = tid;
    float hs = red[0][d] + red[1][d] + red[2][d] + red[3][d];
    float tta = fmaxf(bea[0], 0.f);
    float wgt = (tta > 0.f && cnt > 0)
                    ? __builtin_amdgcn_rcpf((float)cnt)
                    : (1.f / (float)NN);
    hs *= wgt;  // H_sum[i][d]

    float dotv = bw[d];
#pragma unroll 8
    for (int k = 0; k < DD; ++k) {
      float hk = __shfl(hs, k);
      dotv = fmaf(hk, Ww[k * DD + d], dotv);
    }
    float s = dotv, qq = dotv * dotv;
#pragma unroll
    for (int m = 1; m < 64; m <<= 1) {
      s += __shfl_xor(s, m);
      qq += __shfl_xor(qq, m);
    }
    float u = s * (1.f / DD);
    float var2 = qq * (1.f / DD) - u * u;
    float inv = __builtin_amdgcn_rsqf(var2 + EPSF);
    float val = fmaxf(0.f, fmaf(gw[d], (dotv - u) * inv, bew[d]));
    float Cv = val + cn[i * DD + d];
    out[i * DD + d] = hidden[i * DD + d] + fast_tanh(Cv);
    out[NN * DD + i * DD + d] = Cv;
  }
}

extern "C" void kernel_launch(void* const* d_in, const int* in_sizes, int n_in,
                              void* d_out, int out_size, void* d_ws,
                              size_t ws_size, hipStream_t stream) {
  const float* corr = (const float*)d_in[0];
  const int* nei = (const int*)d_in[1];
  // d_in[2] nei_num: unused by the reference math
  const float* hidden = (const float*)d_in[3];
  const float* cn = (const float*)d_in[4];
  const float* Wr = (const float*)d_in[5];
  const float* br = (const float*)d_in[6];
  const float* gr = (const float*)d_in[7];
  const float* ber = (const float*)d_in[8];
  const float* Wg = (const float*)d_in[9];
  const float* bg = (const float*)d_in[10];
  const float* gg = (const float*)d_in[11];
  const float* beg = (const float*)d_in[12];
  // d_in[13..15] W_a/b_a/g_a: cancel analytically
  const float* bea = (const float*)d_in[16];
  const float* Ww = (const float*)d_in[17];
  const float* bw = (const float*)d_in[18];
  const float* gw = (const float*)d_in[19];
  const float* bew = (const float*)d_in[20];
  float* out = (float*)d_out;

  float* ws = (float*)d_ws;
  // float-offset layout (all 16B aligned):
  float* A_pre = ws;                              // 49152
  float2v* BH = (float2v*)(ws + 49152);           // 98304 floats
  float4v* KT = (float4v*)(ws + 147456);          // 256 floats
  float2v* GB = (float2v*)(ws + 147712);          // 128 floats
  float* evec = ws + 147840;                      // 8 (pad to 16)
  unsigned short* WgT = (unsigned short*)(ws + 147856);  // 4096 shorts

  prep_kernel<<<NN / 4 + 1, 256, 0, stream>>>(hidden, Wg, bg, Wr, br, gr, ber,
                                              gg, beg, A_pre, BH, KT, GB, evec,
                                              WgT);
  gat_kernel<<<NN, 256, 0, stream>>>((const int*)nei, (const float2v*)corr,
                                     A_pre, BH, KT, GB, evec, WgT, hidden, cn,
                                     bea, Ww, bw, gw, bew, out);
}

// Round 6
// 134.466 us; speedup vs baseline: 3.7681x; 1.1054x over previous
//
#include <hip/hip_runtime.h>

// GATraj fused kernels for MI355X (gfx950) — round 6.
//
// Math simplifications (verified passing rounds 1-5):
//  * LN over the size-1 W_a channel == be_a exactly -> Pos uniform 1/cnt_i.
//  * tmp @ W_g splits; h_i/h_j parts precomputed (A_pre, BH).
//  * r-LayerNorm analytic via 6 moments of centered W_r (KT table).
//
// Round-6 (r5 post-mortem: 3 waves/SIMD grid cap + KT global loads in the
// R-build chain -> occupancy 9.3%, VALUBusy 21%): 512-thread blocks (8 waves,
// 6/SIMD cap), 16-pair tiles per wave, KT in registers (k=lane) with 3-shuffle
// per-pair broadcast, launch_bounds(512,4) to cap VGPR at 128. Keeps natives,
// WgT pack, hoisted BH gathers, in-block close. No device-scope sync.

#define NN 768
#define DD 64
#define EPSF 1e-5f
#define LOG2E 1.44269504f

typedef __attribute__((ext_vector_type(8))) short short8;
typedef __attribute__((ext_vector_type(4))) float float4v;
typedef __attribute__((ext_vector_type(2))) float float2v;

__device__ __forceinline__ unsigned short f2bf(float f) {
  unsigned int u = __float_as_uint(f);
  u += 0x7fffu + ((u >> 16) & 1u);  // round-to-nearest-even
  return (unsigned short)(u >> 16);
}

__device__ __forceinline__ float fast_tanh(float x) {
  float e = __builtin_amdgcn_exp2f(fminf(x, 20.f) * (2.f * LOG2E));
  return (e - 1.f) * __builtin_amdgcn_rcpf(e + 1.f);
}

// ---------------------------------------------------------------------------
// Prep kernel, grid = 193 blocks x 256 threads (unchanged from r5):
//   bid < 192  : A_pre / {B_pre,hidden} packed GEMVs (wave per row, 4 rows)
//   bid == 192 : transposed bf16 Wg_lo pack + W_r moments -> KT/GB/evec
// ---------------------------------------------------------------------------
__global__ __launch_bounds__(256) void prep_kernel(
    const float* __restrict__ hidden, const float* __restrict__ Wg,
    const float* __restrict__ bg, const float* __restrict__ Wr,
    const float* __restrict__ br, const float* __restrict__ gr,
    const float* __restrict__ ber, const float* __restrict__ gg,
    const float* __restrict__ beg, float* __restrict__ A_pre,
    float2v* __restrict__ BH, float4v* __restrict__ KT,
    float2v* __restrict__ GB, float* __restrict__ evec,
    unsigned short* __restrict__ WgT) {
  const int bid = blockIdx.x;
  const int tid = threadIdx.x;

  if (bid == NN / 4) {
    for (int idx = tid; idx < DD * DD; idx += 256) {
      int n = idx >> 6, k = idx & 63;
      WgT[idx] = f2bf(Wg[k * DD + n]);
    }
    if (tid < 64) {  // wave 0: W_r moments, KT, GB, evec
      int t = tid;
      float w0 = Wr[t], w1 = Wr[DD + t], bb = br[t];
      float m0 = w0, m1 = w1, mb = bb;
      for (int m = 1; m < 64; m <<= 1) {
        m0 += __shfl_xor(m0, m);
        m1 += __shfl_xor(m1, m);
        mb += __shfl_xor(mb, m);
      }
      m0 *= (1.f / DD);
      m1 *= (1.f / DD);
      mb *= (1.f / DD);
      float a0 = w0 - m0, a1 = w1 - m1, ab = bb - mb;
      float grt = gr[t];
      float4v kt;
      kt[0] = grt * a0;
      kt[1] = grt * a1;
      kt[2] = grt * ab;
      kt[3] = ber[t];
      KT[t] = kt;
      // GB packs the sigmoid-folded LN affine: {-log2e*gg, -log2e*beg}
      float2v gb;
      gb[0] = -LOG2E * gg[t];
      gb[1] = -LOG2E * beg[t];
      GB[t] = gb;
      float e00 = a0 * a0, e11 = a1 * a1, ebb = ab * ab;
      float e01 = a0 * a1, e0b = a0 * ab, e1b = a1 * ab;
      for (int m = 1; m < 64; m <<= 1) {
        e00 += __shfl_xor(e00, m);
        e11 += __shfl_xor(e11, m);
        ebb += __shfl_xor(ebb, m);
        e01 += __shfl_xor(e01, m);
        e0b += __shfl_xor(e0b, m);
        e1b += __shfl_xor(e1b, m);
      }
      if (t == 0) {
        evec[0] = e00 * (1.f / DD);
        evec[1] = e11 * (1.f / DD);
        evec[2] = ebb * (1.f / DD);
        evec[3] = e01 * (1.f / DD);
        evec[4] = e0b * (1.f / DD);
        evec[5] = e1b * (1.f / DD);
      }
    }
    return;
  }

  const int w = tid >> 6;
  const int lane = tid & 63;
  const int i = bid * 4 + w;
  float hv = hidden[i * DD + lane];
  float a = bg[lane];
  float b = 0.f;
#pragma unroll 8
  for (int k = 0; k < DD; ++k) {
    float hk = __shfl(hv, k);
    a = fmaf(hk, Wg[(DD + k) * DD + lane], a);
    b = fmaf(hk, Wg[(2 * DD + k) * DD + lane], b);
  }
  A_pre[i * DD + lane] = a;
  float2v bh2;
  bh2[0] = b;
  bh2[1] = hv;
  BH[i * DD + lane] = bh2;
}

// ---------------------------------------------------------------------------
// Monolith: one block per row i (768 x 512 = 8 waves). Compact in LDS; each
// wave independently processes 16-pair tiles (stride 128); in-block close.
// ---------------------------------------------------------------------------
__global__ __launch_bounds__(512, 4) void gat_kernel(
    const int* __restrict__ nei, const float2v* __restrict__ corr2,
    const float* __restrict__ A_pre, const float2v* __restrict__ BH,
    const float4v* __restrict__ KT, const float2v* __restrict__ GB,
    const float* __restrict__ evec, const unsigned short* __restrict__ WgT,
    const float* __restrict__ hidden, const float* __restrict__ cn,
    const float* __restrict__ bea, const float* __restrict__ Ww,
    const float* __restrict__ bw, const float* __restrict__ gw,
    const float* __restrict__ bew, float* __restrict__ out) {
  __shared__ __align__(16) unsigned short Rt[8][16 * 72];  // per-wave slice
  __shared__ short Lst[NN];
  __shared__ float red[8][DD];
  __shared__ int cLds;

  const int i = blockIdx.x;
  const int tid = threadIdx.x;
  const int wid = tid >> 6;
  const int lane = tid & 63;
  const int quad = lane >> 4;
  const int nl = lane & 15;
  const int p16 = lane & 15;  // pair slot within the wave's 16-pair tile

  if (tid == 0) cLds = 0;
  __syncthreads();
  {
    int jj = tid;
    if (nei[i * NN + jj] > 0) {
      int idx = atomicAdd(&cLds, 1);
      Lst[idx] = (short)jj;
    }
    jj = tid + 512;
    if (jj < NN && nei[i * NN + jj] > 0) {
      int idx = atomicAdd(&cLds, 1);
      Lst[idx] = (short)jj;
    }
  }
  __syncthreads();
  const int cnt = cLds;

  // Hoisted constants.
  const float e00 = evec[0], e11 = evec[1], ebb = evec[2];
  const float e01 = evec[3], e0b = evec[4], e1b = evec[5];
  const float4v kt = KT[lane];  // k = lane: {gr*w0h, gr*w1h, gr*bh, ber}

  short8 Bf[2][4];
#pragma unroll
  for (int ks = 0; ks < 2; ++ks)
#pragma unroll
    for (int nt = 0; nt < 4; ++nt)
      __builtin_memcpy(&Bf[ks][nt],
                       &WgT[(nt * 16 + nl) * DD + ks * 32 + quad * 8], 16);

  float ngg[4], nbeg[4], pre4[4];
#pragma unroll
  for (int nt = 0; nt < 4; ++nt) {
    int d = nt * 16 + nl;
    float2v gb = GB[d];
    ngg[nt] = gb[0];   // -log2e * gg
    nbeg[nt] = gb[1];  // -log2e * beg
    pre4[nt] = A_pre[i * DD + d];
  }

  float accT[4] = {0.f, 0.f, 0.f, 0.f};

  // Wave wid: tiles [wid*16 + it*128, +16).
  for (int base = wid * 16; base < cnt; base += 128) {
    int pg = base + p16;
    int jp = (int)Lst[pg < cnt ? pg : cnt - 1];
    float2v cc = corr2[i * NN + jp];
    float var = cc[0] * cc[0] * e00 + cc[1] * cc[1] * e11 + ebb +
                2.f * (cc[0] * cc[1] * e01 + cc[0] * e0b + cc[1] * e1b);
    float iv = __builtin_amdgcn_rsqf(var + EPSF);

    // R build: lane==k writes 16 rows; (c0,c1,iv) broadcast from lane q.
#pragma unroll
    for (int q = 0; q < 16; ++q) {
      float sc0 = __shfl(cc[0], q);
      float sc1 = __shfl(cc[1], q);
      float siv = __shfl(iv, q);
      float s3 = fmaf(sc0, kt[0], fmaf(sc1, kt[1], kt[2]));
      float r = fmaxf(0.f, fmaf(siv, s3, kt[3]));
      Rt[wid][q * 72 + lane] = f2bf(r);
    }
    // Drain LDS writes (same-wave visibility; no barrier needed).
    __builtin_amdgcn_fence(__ATOMIC_ACQ_REL, "workgroup");

    // Gathers hoisted before MFMA so latency hides under matrix work.
    int jpr[4];
    float pv[4];
#pragma unroll
    for (int rr = 0; rr < 4; ++rr) {
      int pl = quad * 4 + rr;  // C layout: m = quad*4 + reg
      jpr[rr] = __shfl(jp, pl);
      pv[rr] = (base + pl < cnt) ? 1.f : 0.f;
    }
    float2v bh2[4][4];
#pragma unroll
    for (int rr = 0; rr < 4; ++rr)
#pragma unroll
      for (int nt = 0; nt < 4; ++nt)
        bh2[rr][nt] = BH[jpr[rr] * DD + nt * 16 + nl];

    short8 a0, a1;
    __builtin_memcpy(&a0, &Rt[wid][nl * 72 + quad * 8], 16);
    __builtin_memcpy(&a1, &Rt[wid][nl * 72 + 32 + quad * 8], 16);
    float4v acc[4];
#pragma unroll
    for (int nt = 0; nt < 4; ++nt) {
      float4v z = {0.f, 0.f, 0.f, 0.f};
      z = __builtin_amdgcn_mfma_f32_16x16x32_bf16(a0, Bf[0][nt], z, 0, 0, 0);
      z = __builtin_amdgcn_mfma_f32_16x16x32_bf16(a1, Bf[1][nt], z, 0, 0, 0);
      acc[nt] = z;
    }

    float y[4][4];
#pragma unroll
    for (int nt = 0; nt < 4; ++nt)
#pragma unroll
      for (int rr = 0; rr < 4; ++rr)
        y[nt][rr] = acc[nt][rr] + pre4[nt] + bh2[rr][nt][0];
#pragma unroll
    for (int rr = 0; rr < 4; ++rr) {
      float s = y[0][rr] + y[1][rr] + y[2][rr] + y[3][rr];
      float qq = y[0][rr] * y[0][rr] + y[1][rr] * y[1][rr] +
                 y[2][rr] * y[2][rr] + y[3][rr] * y[3][rr];
#pragma unroll
      for (int m = 1; m < 16; m <<= 1) {
        s += __shfl_xor(s, m);
        qq += __shfl_xor(qq, m);
      }
      float u = s * (1.f / DD);
      float vv = qq * (1.f / DD) - u * u;
      float inv = __builtin_amdgcn_rsqf(vv + EPSF);
#pragma unroll
      for (int nt = 0; nt < 4; ++nt) {
        // gate = sigmoid(gg*(y-u)*inv + beg) = rcp(1 + exp2(ngg*(y-u)*inv + nbeg))
        float e = __builtin_amdgcn_exp2f(fmaf(ngg[nt] * (y[nt][rr] - u), inv, nbeg[nt]));
        float gate = __builtin_amdgcn_rcpf(1.f + e);
        accT[nt] = fmaf(gate * pv[rr], bh2[rr][nt][1], accT[nt]);
      }
    }
  }

  // Per-wave partials -> LDS (all 8 waves reach here).
#pragma unroll
  for (int nt = 0; nt < 4; ++nt) {
    accT[nt] += __shfl_xor(accT[nt], 16);
    accT[nt] += __shfl_xor(accT[nt], 32);
  }
  if (lane < 16) {
#pragma unroll
    for (int nt = 0; nt < 4; ++nt) red[wid][nt * 16 + nl] = accT[nt];
  }
  __syncthreads();

  if (tid < 64) {  // wave 0 closes the row
    const int d = tid;
    float hs = 0.f;
#pragma unroll
    for (int w = 0; w < 8; ++w) hs += red[w][d];
    float tta = fmaxf(bea[0], 0.f);
    float wgt = (tta > 0.f && cnt > 0) ? __builtin_amdgcn_rcpf((float)cnt)
                                       : (1.f / (float)NN);
    hs *= wgt;  // H_sum[i][d]

    float dotv = bw[d];
#pragma unroll 8
    for (int k = 0; k < DD; ++k) {
      float hk = __shfl(hs, k);
      dotv = fmaf(hk, Ww[k * DD + d], dotv);
    }
    float s = dotv, qq = dotv * dotv;
#pragma unroll
    for (int m = 1; m < 64; m <<= 1) {
      s += __shfl_xor(s, m);
      qq += __shfl_xor(qq, m);
    }
    float u = s * (1.f / DD);
    float var2 = qq * (1.f / DD) - u * u;
    float inv = __builtin_amdgcn_rsqf(var2 + EPSF);
    float val = fmaxf(0.f, fmaf(gw[d], (dotv - u) * inv, bew[d]));
    float Cv = val + cn[i * DD + d];
    out[i * DD + d] = hidden[i * DD + d] + fast_tanh(Cv);
    out[NN * DD + i * DD + d] = Cv;
  }
}

extern "C" void kernel_launch(void* const* d_in, const int* in_sizes, int n_in,
                              void* d_out, int out_size, void* d_ws,
                              size_t ws_size, hipStream_t stream) {
  const float* corr = (const float*)d_in[0];
  const int* nei = (const int*)d_in[1];
  // d_in[2] nei_num: unused by the reference math
  const float* hidden = (const float*)d_in[3];
  const float* cn = (const float*)d_in[4];
  const float* Wr = (const float*)d_in[5];
  const float* br = (const float*)d_in[6];
  const float* gr = (const float*)d_in[7];
  const float* ber = (const float*)d_in[8];
  const float* Wg = (const float*)d_in[9];
  const float* bg = (const float*)d_in[10];
  const float* gg = (const float*)d_in[11];
  const float* beg = (const float*)d_in[12];
  // d_in[13..15] W_a/b_a/g_a: cancel analytically
  const float* bea = (const float*)d_in[16];
  const float* Ww = (const float*)d_in[17];
  const float* bw = (const float*)d_in[18];
  const float* gw = (const float*)d_in[19];
  const float* bew = (const float*)d_in[20];
  float* out = (float*)d_out;

  float* ws = (float*)d_ws;
  float* A_pre = ws;                              // 49152
  float2v* BH = (float2v*)(ws + 49152);           // 98304 floats
  float4v* KT = (float4v*)(ws + 147456);          // 256 floats
  float2v* GB = (float2v*)(ws + 147712);          // 128 floats
  float* evec = ws + 147840;                      // 8 (pad to 16)
  unsigned short* WgT = (unsigned short*)(ws + 147856);  // 4096 shorts

  prep_kernel<<<NN / 4 + 1, 256, 0, stream>>>(hidden, Wg, bg, Wr, br, gr, ber,
                                              gg, beg, A_pre, BH, KT, GB, evec,
                                              WgT);
  gat_kernel<<<NN, 512, 0, stream>>>((const int*)nei, (const float2v*)corr,
                                     A_pre, BH, KT, GB, evec, WgT, hidden, cn,
                                     bea, Ww, bw, gw, bew, out);
}